// Round 10
// baseline (339.875 us; speedup 1.0000x reference)
//
#include <hip/hip_runtime.h>

#define L 21
#define NVOX 4096
#define ITERS 5
#define NU 210      // monomials of degree <= 4 in 6 vars
#define UPAD 224    // padded rows (210..223 are zero)
#define NBLK 64
#define TPB 1024
#define NSPLIT 16   // u-splits in P3
#define USPL 14     // u per split (16*14 = 224)
#define READY_MAGIC 0x13579BDF

// ---- agent-coherent accessors: sc1 ops that hit the LLC, bypassing the ----
// ---- non-coherent per-XCD L2s.  No fences needed anywhere.             ----
__device__ __forceinline__ float ld_cg(const float* p) {
    return __hip_atomic_load(p, __ATOMIC_RELAXED, __HIP_MEMORY_SCOPE_AGENT);
}
__device__ __forceinline__ void st_cg(float* p, float v) {
    __hip_atomic_store(p, v, __ATOMIC_RELAXED, __HIP_MEMORY_SCOPE_AGENT);
}

// Fence-free grid barrier: __syncthreads' implicit vmcnt(0) drain means all
// of this block's sc1 stores are already at the LLC (globally visible);
// arrive/poll are relaxed agent atomics (also LLC).  Workgroup-scope fences
// are waitcnt-only (no buffer_wbl2 / buffer_inv — the R6 killer).
__device__ __forceinline__ void gbar(int* cnt) {
    __builtin_amdgcn_fence(__ATOMIC_RELEASE, "workgroup");
    __syncthreads();
    if (threadIdx.x == 0) {
        __hip_atomic_fetch_add(cnt, 1, __ATOMIC_RELAXED, __HIP_MEMORY_SCOPE_AGENT);
        while (__hip_atomic_load(cnt, __ATOMIC_RELAXED, __HIP_MEMORY_SCOPE_AGENT) < NBLK)
            __builtin_amdgcn_s_sleep(1);
        __builtin_amdgcn_fence(__ATOMIC_ACQUIRE, "workgroup");
    }
    __syncthreads();
}

struct G1Sh { float qs[L][64]; float red[4][UPAD][22]; };
struct SpSh { float buf[NVOX]; float tmp[NVOX]; float g[16]; };
struct P3Sh {
    float sA[L * UPAD];
    float sN[UPAD];
    float red[22][NSPLIT][64];
    float sw1[L * L];
    float sspn[64][22];
};
union SharedU { G1Sh g1; SpSh sp; P3Sh p3; };

__global__ __launch_bounds__(TPB, 1) void crf_fused(
    const float* __restrict__ img, const float* __restrict__ logits,
    const float* __restrict__ Wsp, const float* __restrict__ Wbi,
    const float* __restrict__ Wc, float* __restrict__ out,
    int* bar, float* __restrict__ Phi, float* __restrict__ nsp,
    float* __restrict__ q, float* __restrict__ spv, float* __restrict__ A2,
    float* __restrict__ cu, float* __restrict__ W1, float* __restrict__ W2)
{
    __shared__ SharedU su;
    __shared__ float scur[64][22];
    const int tid = threadIdx.x;
    const int bid = blockIdx.x;
    const int lane = tid & 63;
    const int wv = tid >> 6;

    // ---- ready-gate (poison-tolerant, relaxed polls) ----
    if (bid == 0 && tid == 0) {
        for (int k = 0; k < 12; k++)
            __hip_atomic_store(bar + k * 16, 0, __ATOMIC_RELAXED, __HIP_MEMORY_SCOPE_AGENT);
        __hip_atomic_store(bar + 255, READY_MAGIC, __ATOMIC_RELAXED, __HIP_MEMORY_SCOPE_AGENT);
    }
    if (tid == 0) {
        while (__hip_atomic_load(bar + 255, __ATOMIC_RELAXED, __HIP_MEMORY_SCOPE_AGENT) != READY_MAGIC)
            __builtin_amdgcn_s_sleep(1);
        __builtin_amdgcn_fence(__ATOMIC_ACQUIRE, "workgroup");
    }
    __syncthreads();
    int bk = 0;

    // ================= Phase AB: Phi + nsp + q0 + tables =================
    {
        int i = bid * 64 + lane;
        int z = i >> 8, yy = (i >> 4) & 15, xx = i & 15;
        const float ia = 1.0f / 67.0f, ib = 1.0f / 3.0f;
        float f[6];
        f[0] = (float)z * ia; f[1] = (float)yy * ia; f[2] = (float)xx * ia;
        f[3] = img[i] * ib; f[4] = img[NVOX + i] * ib; f[5] = img[2 * NVOX + i] * ib;
        float p[6][5];
#pragma unroll
        for (int c = 0; c < 6; c++) {
            p[c][0] = 1.f;
#pragma unroll
            for (int k = 1; k < 5; k++) p[c][k] = p[c][k - 1] * f[c];
        }
        float hsv = 0.5f * (f[0]*f[0] + f[1]*f[1] + f[2]*f[2] +
                            f[3]*f[3] + f[4]*f[4] + f[5]*f[5]);
        float e0 = __expf(-hsv);
        int ulo = wv * 14, uhi = ulo + 14;
        int u = 0;
        for (int a0 = 0; a0 <= 4; a0++)
        for (int a1 = 0; a1 <= 4 - a0; a1++)
        for (int a2 = 0; a2 <= 4 - a0 - a1; a2++)
        for (int a3 = 0; a3 <= 4 - a0 - a1 - a2; a3++)
        for (int a4 = 0; a4 <= 4 - a0 - a1 - a2 - a3; a4++)
        for (int a5 = 0; a5 <= 4 - a0 - a1 - a2 - a3 - a4; a5++) {
            if (u >= ulo && u < uhi)
                st_cg(&Phi[(size_t)u * NVOX + i],
                      e0 * p[0][a0] * p[1][a1] * p[2][a2] * p[3][a3] * p[4][a4] * p[5][a5]);
            u++;
        }
        if (ulo >= NU)   // wave 15: pad rows 210..223
            for (int uz = ulo; uz < uhi; uz++)
                st_cg(&Phi[(size_t)uz * NVOX + i], 0.f);
        if (wv == 0) {
            float hz = 0.f, hy = 0.f, hx = 0.f;
            for (int t = 0; t < 16; t++) {
                float dz = (float)(z - t), dy = (float)(yy - t), dx = (float)(xx - t);
                hz += __expf(-0.5f * dz * dz);
                hy += __expf(-0.5f * dy * dy);
                hx += __expf(-0.5f * dx * dx);
            }
            st_cg(&nsp[i], hz * hy * hx);
        }
        if (wv == 1) {   // softmax of logits -> q (iteration 0)
            float vals[L]; float mx = -1e30f;
#pragma unroll
            for (int l = 0; l < L; l++) { vals[l] = logits[l * NVOX + i]; mx = fmaxf(mx, vals[l]); }
            float sum = 0.f;
#pragma unroll
            for (int l = 0; l < L; l++) { vals[l] = __expf(vals[l] - mx); sum += vals[l]; }
            float inv = 1.f / sum;
#pragma unroll
            for (int l = 0; l < L; l++) st_cg(&q[l * NVOX + i], vals[l] * inv);
        }
        if (bid == 63) {
            for (int e = tid; e < L * L; e += TPB) {
                int r = e / L, c = e % L;
                float s1 = 0.f, s2 = 0.f;
                for (int k = 0; k < L; k++) {
                    float wc = Wc[r * L + k];
                    s1 = fmaf(wc, Wsp[k * L + c], s1);
                    s2 = fmaf(wc, Wbi[k * L + c], s2);
                }
                st_cg(&W1[e], s1); st_cg(&W2[e], s2);
            }
        }
        if (bid == 62 && tid < 256) {
            const float invf[5] = {1.f, 1.f, 0.5f, 1.f / 6.f, 1.f / 24.f};
            float mine = 0.f;   // stays 0 for tid >= NU
            int v = 0;
            for (int a0 = 0; a0 <= 4; a0++)
            for (int a1 = 0; a1 <= 4 - a0; a1++)
            for (int a2 = 0; a2 <= 4 - a0 - a1; a2++)
            for (int a3 = 0; a3 <= 4 - a0 - a1 - a2; a3++)
            for (int a4 = 0; a4 <= 4 - a0 - a1 - a2 - a3; a4++)
            for (int a5 = 0; a5 <= 4 - a0 - a1 - a2 - a3 - a4; a5++) {
                if (v == tid)
                    mine = invf[a0] * invf[a1] * invf[a2] * invf[a3] * invf[a4] * invf[a5];
                v++;
            }
            st_cg(&cu[tid], mine);
        }
        if (bid == 61)
            for (int e = tid; e < 2 * 22 * UPAD; e += TPB) st_cg(&A2[e], 0.f);
    }
    gbar(bar + (bk++) * 16);

    const int i0 = bid * 64;
    const int v = tid & 63;
    const int s = tid >> 6;          // 0..15

    for (int it = 0; it < ITERS; it++) {
        float* A2cur  = A2 + (it & 1) * 22 * UPAD;
        float* A2next = A2 + ((it + 1) & 1) * 22 * UPAD;

        // ===== P2: g1 (i-major, all 64 blocks) then spatial (blocks 0..20) =====
        for (int e = tid; e < L * 64; e += TPB) {
            int m = e >> 6, ii = e & 63;
            su.g1.qs[m][ii] = ld_cg(&q[m * NVOX + i0 + ii]);
        }
        __syncthreads();
        {
            int quarter = tid >> 8, u = tid & 255;
            if (u < UPAD) {
                float acc[22];
#pragma unroll
                for (int m = 0; m < 22; m++) acc[m] = 0.f;
                const float4* prow = (const float4*)(Phi + (size_t)u * NVOX + i0 + quarter * 16);
#pragma unroll
                for (int c = 0; c < 4; c++) {
                    float4 pv = prow[c];
                    float ph[4] = {pv.x, pv.y, pv.z, pv.w};
#pragma unroll
                    for (int e = 0; e < 4; e++) {
                        int ii = quarter * 16 + c * 4 + e;
                        acc[21] += ph[e];
#pragma unroll
                        for (int m = 0; m < L; m++)
                            acc[m] = fmaf(ph[e], su.g1.qs[m][ii], acc[m]);
                    }
                }
#pragma unroll
                for (int m = 0; m < 22; m++) su.g1.red[quarter][u][m] = acc[m];
            }
        }
        __syncthreads();
        if (tid < UPAD) {
            float Mg[22];
#pragma unroll
            for (int m = 0; m < 22; m++)
                Mg[m] = su.g1.red[0][tid][m] + su.g1.red[1][tid][m] +
                        su.g1.red[2][tid][m] + su.g1.red[3][tid][m];
            float cuv = cu[tid];
#pragma unroll
            for (int l = 0; l < L; l++) {
                float d = 0.f;
#pragma unroll
                for (int m = 0; m < L; m++)
                    d = fmaf(W2[l * L + m], Mg[m], d);
                atomicAdd(&A2cur[l * UPAD + tid], cuv * d);
            }
            atomicAdd(&A2cur[L * UPAD + tid], cuv * Mg[21]);
        }
        __syncthreads();   // union transition g1 -> spatial
        if (bid < L) {
            int l = bid;
            if (tid < 16) su.sp.g[tid] = __expf(-0.5f * (float)(tid * tid));
            for (int k = 0; k < 4; k++)
                su.sp.buf[tid + 1024 * k] = ld_cg(&q[l * NVOX + tid + 1024 * k]);
            __syncthreads();
            for (int k = 0; k < 4; k++) {
                int idx = tid + 1024 * k;
                int x = idx & 15, base = idx & ~15;
                float ssum = 0.f;
#pragma unroll
                for (int t = 0; t < 16; t++) {
                    int d = x - t; d = d < 0 ? -d : d;
                    ssum += su.sp.g[d] * su.sp.buf[base + t];
                }
                su.sp.tmp[idx] = ssum;
            }
            __syncthreads();
            for (int k = 0; k < 4; k++) {
                int idx = tid + 1024 * k;
                int y = (idx >> 4) & 15, base = idx & ~(15 << 4);
                float ssum = 0.f;
#pragma unroll
                for (int t = 0; t < 16; t++) {
                    int d = y - t; d = d < 0 ? -d : d;
                    ssum += su.sp.g[d] * su.sp.tmp[base + (t << 4)];
                }
                su.sp.buf[idx] = ssum;
            }
            __syncthreads();
            for (int k = 0; k < 4; k++) {
                int idx = tid + 1024 * k;
                int z = idx >> 8, base = idx & 255;
                float ssum = 0.f;
#pragma unroll
                for (int t = 0; t < 16; t++) {
                    int d = z - t; d = d < 0 ? -d : d;
                    ssum += su.sp.g[d] * su.sp.buf[base + (t << 8)];
                }
                st_cg(&spv[l * NVOX + idx], ssum);
            }
        }
        gbar(bar + (bk++) * 16);

        // ================= P3: g2 + combine + softmax =================
        if (bid < 5) {   // zero next iteration's A2 buffer
            int e = bid * TPB + tid;
            if (e < 22 * UPAD) st_cg(&A2next[e], 0.f);
        }
        for (int e = tid; e < L * UPAD; e += TPB) su.p3.sA[e] = ld_cg(&A2cur[e]);
        for (int e = tid; e < UPAD; e += TPB) su.p3.sN[e] = ld_cg(&A2cur[L * UPAD + e]);
        for (int e = tid; e < L * L; e += TPB) su.p3.sw1[e] = W1[e];
        {
            float rsp = 1.f / nsp[i0 + v];
            for (int m = s; m < L; m += NSPLIT)
                su.p3.sspn[v][m] = ld_cg(&spv[m * NVOX + i0 + v]) * rsp;
        }
        __syncthreads();
        {
            float acc[L], accN = 0.f;
#pragma unroll
            for (int m = 0; m < L; m++) acc[m] = 0.f;
            int u0 = s * USPL;
            for (int uu = 0; uu < USPL; uu++) {
                float p = Phi[(size_t)(u0 + uu) * NVOX + i0 + v];
#pragma unroll
                for (int m = 0; m < L; m++)
                    acc[m] = fmaf(su.p3.sA[m * UPAD + u0 + uu], p, acc[m]);
                accN = fmaf(su.p3.sN[u0 + uu], p, accN);
            }
#pragma unroll
            for (int m = 0; m < L; m++) su.p3.red[m][s][v] = acc[m];
            su.p3.red[21][s][v] = accN;
        }
        __syncthreads();
        {
            float b21 = 0.f;
#pragma unroll
            for (int ss = 0; ss < NSPLIT; ss++) b21 += su.p3.red[21][ss][v];
            float rbi = 1.f / b21;
            for (int l = s; l < L; l += NSPLIT) {
                float bl = 0.f;
#pragma unroll
                for (int ss = 0; ss < NSPLIT; ss++) bl += su.p3.red[l][ss][v];
                float r = bl * rbi;
#pragma unroll
                for (int m = 0; m < L; m++)
                    r = fmaf(su.p3.sw1[l * L + m], su.p3.sspn[v][m], r);
                r += logits[l * NVOX + i0 + v];
                scur[v][l] = r;
                if (it == ITERS - 1) out[l * NVOX + i0 + v] = r;
            }
        }
        __syncthreads();
        if (it < ITERS - 1) {
            if (tid < 64) {
                float vals[L]; float mx = -1e30f;
#pragma unroll
                for (int l = 0; l < L; l++) { vals[l] = scur[tid][l]; mx = fmaxf(mx, vals[l]); }
                float sum = 0.f;
#pragma unroll
                for (int l = 0; l < L; l++) { vals[l] = __expf(vals[l] - mx); sum += vals[l]; }
                float inv = 1.f / sum;
#pragma unroll
                for (int l = 0; l < L; l++) st_cg(&q[l * NVOX + i0 + tid], vals[l] * inv);
            }
            gbar(bar + (bk++) * 16);
        }
    }

    // cleanup so an un-poisoned relaunch still re-inits (stream order protects us)
    if (bid == 0 && tid == 0)
        __hip_atomic_store(bar + 255, 0, __ATOMIC_RELAXED, __HIP_MEMORY_SCOPE_AGENT);
}

extern "C" void kernel_launch(void* const* d_in, const int* in_sizes, int n_in,
                              void* d_out, int out_size, void* d_ws, size_t ws_size,
                              hipStream_t stream) {
    const float* image  = (const float*)d_in[0];
    const float* logits = (const float*)d_in[1];
    const float* Wsp    = (const float*)d_in[2];
    const float* Wbi    = (const float*)d_in[3];
    const float* Wc     = (const float*)d_in[4];
    float* out = (float*)d_out;

    char* ws = (char*)d_ws;
    int*   bar   = (int*)ws;   ws += 1024;
    float* Phi   = (float*)ws; ws += (size_t)UPAD * NVOX * sizeof(float);    // 3.67 MB
    float* nsp   = (float*)ws; ws += (size_t)NVOX * sizeof(float);
    float* q     = (float*)ws; ws += (size_t)L * NVOX * sizeof(float);
    float* spv   = (float*)ws; ws += (size_t)L * NVOX * sizeof(float);
    float* A2    = (float*)ws; ws += (size_t)2 * 22 * UPAD * sizeof(float);  // double buffer
    float* cu    = (float*)ws; ws += (size_t)256 * sizeof(float);
    float* W1    = (float*)ws; ws += (size_t)L * L * sizeof(float);
    float* W2    = (float*)ws; ws += (size_t)L * L * sizeof(float);

    crf_fused<<<NBLK, TPB, 0, stream>>>(image, logits, Wsp, Wbi, Wc, out,
                                        bar, Phi, nsp, q, spv, A2, cu, W1, W2);
}

// Round 11
// 232.950 us; speedup vs baseline: 1.4590x; 1.4590x over previous
//
#include <hip/hip_runtime.h>

#define L 21
#define NVOX 4096
#define ITERS 5
#define NU 210      // monomials of degree <= 4 in 6 vars
#define UPAD 224    // padded rows (210..223 are zero)
#define VPB 16      // voxels per block (P3)
#define NSPLIT 16   // u-splits in P3
#define USPL 14     // u per split (16*14 = 224)
#define NG1B 56     // g1 blocks: 56 x 4 u-chunks = 224 u

// ---------------------------------------------------------------------------
// Phase AB (67 blocks x 256): Phi + nsp + q0(softmax of logits) + W-folds +
// cu table + zero both A2 buffers (22 rows each; row 21 = normalizer).
// ---------------------------------------------------------------------------
__global__ __launch_bounds__(256) void phase_ab(
    const float* __restrict__ img, const float* __restrict__ logits,
    const float* __restrict__ Wsp, const float* __restrict__ Wbi,
    const float* __restrict__ Wc,
    float* __restrict__ Phi, float* __restrict__ nsp, float* __restrict__ q,
    float* __restrict__ cu, float* __restrict__ W1, float* __restrict__ W2,
    float* __restrict__ A2)
{
    const int tid = threadIdx.x;
    const int bid = blockIdx.x;
    if (bid < 64) {
        int lane = tid & 63, w = tid >> 6;
        int i = bid * 64 + lane;
        int z = i >> 8, yy = (i >> 4) & 15, xx = i & 15;
        const float ia = 1.0f / 67.0f, ib = 1.0f / 3.0f;
        float f[6];
        f[0] = (float)z * ia; f[1] = (float)yy * ia; f[2] = (float)xx * ia;
        f[3] = img[i] * ib; f[4] = img[NVOX + i] * ib; f[5] = img[2 * NVOX + i] * ib;
        float p[6][5];
#pragma unroll
        for (int c = 0; c < 6; c++) {
            p[c][0] = 1.f;
#pragma unroll
            for (int k = 1; k < 5; k++) p[c][k] = p[c][k - 1] * f[c];
        }
        float hsv = 0.5f * (f[0]*f[0] + f[1]*f[1] + f[2]*f[2] +
                            f[3]*f[3] + f[4]*f[4] + f[5]*f[5]);
        float e0 = __expf(-hsv);
        int ulo = w * 56, uhi = ulo + 56;
        int u = 0;
        for (int a0 = 0; a0 <= 4; a0++)
        for (int a1 = 0; a1 <= 4 - a0; a1++)
        for (int a2 = 0; a2 <= 4 - a0 - a1; a2++)
        for (int a3 = 0; a3 <= 4 - a0 - a1 - a2; a3++)
        for (int a4 = 0; a4 <= 4 - a0 - a1 - a2 - a3; a4++)
        for (int a5 = 0; a5 <= 4 - a0 - a1 - a2 - a3 - a4; a5++) {
            if (u >= ulo && u < uhi)
                Phi[(size_t)u * NVOX + i] =
                    e0 * p[0][a0] * p[1][a1] * p[2][a2] * p[3][a3] * p[4][a4] * p[5][a5];
            u++;
        }
        if (w == 3)
            for (int uz = NU; uz < UPAD; uz++) Phi[(size_t)uz * NVOX + i] = 0.f;
        if (w == 0) {
            float hz = 0.f, hy = 0.f, hx = 0.f;
            for (int t = 0; t < 16; t++) {
                float dz = (float)(z - t), dy = (float)(yy - t), dx = (float)(xx - t);
                hz += __expf(-0.5f * dz * dz);
                hy += __expf(-0.5f * dy * dy);
                hx += __expf(-0.5f * dx * dx);
            }
            nsp[i] = hz * hy * hx;
        }
        if (w == 1) {   // softmax of logits -> q (iteration 0)
            float vals[L]; float mx = -1e30f;
#pragma unroll
            for (int l = 0; l < L; l++) { vals[l] = logits[l * NVOX + i]; mx = fmaxf(mx, vals[l]); }
            float sum = 0.f;
#pragma unroll
            for (int l = 0; l < L; l++) { vals[l] = __expf(vals[l] - mx); sum += vals[l]; }
            float inv = 1.f / sum;
#pragma unroll
            for (int l = 0; l < L; l++) q[l * NVOX + i] = vals[l] * inv;
        }
    } else if (bid == 64) {
        for (int e = tid; e < L * L; e += 256) {
            int r = e / L, c = e % L;
            float s1 = 0.f, s2 = 0.f;
            for (int k = 0; k < L; k++) {
                float wc = Wc[r * L + k];
                s1 = fmaf(wc, Wsp[k * L + c], s1);
                s2 = fmaf(wc, Wbi[k * L + c], s2);
            }
            W1[e] = s1; W2[e] = s2;
        }
    } else if (bid == 65) {
        const float invf[5] = {1.f, 1.f, 0.5f, 1.f / 6.f, 1.f / 24.f};
        float mine = 0.f;   // stays 0 for tid >= NU
        int v = 0;
        for (int a0 = 0; a0 <= 4; a0++)
        for (int a1 = 0; a1 <= 4 - a0; a1++)
        for (int a2 = 0; a2 <= 4 - a0 - a1; a2++)
        for (int a3 = 0; a3 <= 4 - a0 - a1 - a2; a3++)
        for (int a4 = 0; a4 <= 4 - a0 - a1 - a2 - a3; a4++)
        for (int a5 = 0; a5 <= 4 - a0 - a1 - a2 - a3 - a4; a5++) {
            if (v == tid)
                mine = invf[a0] * invf[a1] * invf[a2] * invf[a3] * invf[a4] * invf[a5];
            v++;
        }
        cu[tid] = mine;
    } else {
        // zero BOTH A2 double-buffers (22 rows each; g1 accumulates atomically)
        for (int e = tid; e < 2 * 22 * UPAD; e += 256) A2[e] = 0.f;
    }
}

// ---------------------------------------------------------------------------
// Phase P2 (77 blocks x 1024):
//  bid<56: g1.  16 waves = 4 u (bid*4 + wv>>2) x 4 i-chunks of 1024 voxels.
//    Per wave: 4 float4-iterations over 22 rows (21 labels + normalizer),
//    butterfly reduce, W2/cu fold, atomicAdd into A2cur rows 0..21.
//    Fat waves: butterfly DS cost amortized over 4x more FMA than R9.
//  bid 56..76: spatial label bid-56.  Separable gaussian TRUNCATED to +-4
//    taps (dropped weight ~7.5e-6) with compile-time g constants — no LDS
//    g[] lookups (128 -> 36 LDS reads per thread per pass).
// ---------------------------------------------------------------------------
__global__ __launch_bounds__(1024) void phase_p2(
    const float* __restrict__ Phi, const float* __restrict__ q,
    const float* __restrict__ cu, const float* __restrict__ W2,
    float* __restrict__ A2cur, float* __restrict__ spv)
{
    __shared__ float buf[NVOX];
    __shared__ float tmp[NVOX];
    const int tid = threadIdx.x;
    const int bid = blockIdx.x;
    const float garr[5] = {1.0f, 0.60653066f, 0.13533528f,
                           0.011108997f, 3.3546263e-4f};
    if (bid < NG1B) {
        const int lane = tid & 63, wv = tid >> 6;
        const int u = bid * 4 + (wv >> 2);
        const int i0 = (wv & 3) * 1024;
        float acc[22];
#pragma unroll
        for (int m = 0; m < 22; m++) acc[m] = 0.f;
        const float4* ph = (const float4*)(Phi + (size_t)u * NVOX + i0);
#pragma unroll
        for (int rep = 0; rep < 4; rep++) {
            int ii = rep * 64 + lane;
            float4 pv = ph[ii];
            acc[21] += pv.x + pv.y + pv.z + pv.w;
#pragma unroll
            for (int m = 0; m < L; m++) {
                float4 qv = ((const float4*)(q + m * NVOX + i0))[ii];
                acc[m] = fmaf(qv.x, pv.x, fmaf(qv.y, pv.y,
                         fmaf(qv.z, pv.z, fmaf(qv.w, pv.w, acc[m]))));
            }
        }
#pragma unroll
        for (int off = 32; off >= 1; off >>= 1)
#pragma unroll
            for (int m = 0; m < 22; m++)
                acc[m] += __shfl_xor(acc[m], off);
        if (lane < 22) {
            float val;
            if (lane < L) {
                float dot = 0.f;
#pragma unroll
                for (int m = 0; m < L; m++)
                    dot = fmaf(W2[lane * L + m], acc[m], dot);
                val = cu[u] * dot;
            } else {
                val = cu[u] * acc[21];
            }
            atomicAdd(&A2cur[lane * UPAD + u], val);
        }
    } else {
        int l = bid - NG1B;
        for (int k = 0; k < 4; k++)
            buf[tid + 1024 * k] = q[l * NVOX + tid + 1024 * k];
        __syncthreads();
        for (int k = 0; k < 4; k++) {
            int idx = tid + 1024 * k;
            int x = idx & 15, base = idx & ~15;
            float ssum = 0.f;
#pragma unroll
            for (int dt = -4; dt <= 4; dt++) {
                int t = x + dt;
                int ad = dt < 0 ? -dt : dt;
                if (t >= 0 && t < 16) ssum = fmaf(garr[ad], buf[base + t], ssum);
            }
            tmp[idx] = ssum;
        }
        __syncthreads();
        for (int k = 0; k < 4; k++) {
            int idx = tid + 1024 * k;
            int y = (idx >> 4) & 15, base = idx & ~(15 << 4);
            float ssum = 0.f;
#pragma unroll
            for (int dt = -4; dt <= 4; dt++) {
                int t = y + dt;
                int ad = dt < 0 ? -dt : dt;
                if (t >= 0 && t < 16) ssum = fmaf(garr[ad], tmp[base + (t << 4)], ssum);
            }
            buf[idx] = ssum;
        }
        __syncthreads();
        for (int k = 0; k < 4; k++) {
            int idx = tid + 1024 * k;
            int z = idx >> 8, base = idx & 255;
            float ssum = 0.f;
#pragma unroll
            for (int dt = -4; dt <= 4; dt++) {
                int t = z + dt;
                int ad = dt < 0 ? -dt : dt;
                if (t >= 0 && t < 16) ssum = fmaf(garr[ad], buf[base + (t << 8)], ssum);
            }
            spv[l * NVOX + idx] = ssum;
        }
    }
}

// ---------------------------------------------------------------------------
// Phase P3: g2 + combine + softmax-for-next-iter.  256 blocks x 16 voxels.
// Reads A2cur rows 0..20 (bilateral) + row 21 (normalizer); zeroes A2next.
// float4 staging of sA/sN.
// ---------------------------------------------------------------------------
__global__ __launch_bounds__(256) void phase_p3(
    const float* __restrict__ Phi, const float* __restrict__ A2cur,
    float* __restrict__ A2next, const float* __restrict__ spv,
    const float* __restrict__ nsp, const float* __restrict__ W1,
    const float* __restrict__ logits, float* __restrict__ q,
    float* __restrict__ out, int last)
{
    __shared__ __align__(16) float sA[L * UPAD];
    __shared__ __align__(16) float sN[UPAD];
    __shared__ float red[22][NSPLIT][VPB];
    __shared__ float sw1[L * L];
    __shared__ float sspn[VPB][22];
    __shared__ float scur[VPB][22];
    const int tid = threadIdx.x;
    const int bid = blockIdx.x;
    const int v = tid & (VPB - 1);
    const int s = tid >> 4;
    const int i16 = bid * VPB + v;

    {   // zero next iteration's A2 buffer (22 rows; first 20 blocks cover it)
        int e = bid * 256 + tid;
        if (e < 22 * UPAD) A2next[e] = 0.f;
    }
    for (int e = tid; e < (L * UPAD) / 4; e += 256)
        ((float4*)sA)[e] = ((const float4*)A2cur)[e];
    if (tid < UPAD / 4)
        ((float4*)sN)[tid] = ((const float4*)(A2cur + L * UPAD))[tid];
    for (int e = tid; e < L * L; e += 256) sw1[e] = W1[e];
    {
        float rsp = 1.f / nsp[i16];
        for (int m = s; m < L; m += NSPLIT)
            sspn[v][m] = spv[m * NVOX + i16] * rsp;
    }
    __syncthreads();
    float acc[L], accN = 0.f;
#pragma unroll
    for (int m = 0; m < L; m++) acc[m] = 0.f;
    int u0 = s * USPL;
    for (int uu = 0; uu < USPL; uu++) {
        float p = Phi[(size_t)(u0 + uu) * NVOX + i16];
#pragma unroll
        for (int m = 0; m < L; m++)
            acc[m] = fmaf(sA[m * UPAD + u0 + uu], p, acc[m]);
        accN = fmaf(sN[u0 + uu], p, accN);
    }
#pragma unroll
    for (int m = 0; m < L; m++) red[m][s][v] = acc[m];
    red[21][s][v] = accN;
    __syncthreads();
    float b21 = 0.f;
#pragma unroll
    for (int ss = 0; ss < NSPLIT; ss++) b21 += red[21][ss][v];
    float rbi = 1.f / b21;
    for (int l = s; l < L; l += NSPLIT) {
        float bl = 0.f;
#pragma unroll
        for (int ss = 0; ss < NSPLIT; ss++) bl += red[l][ss][v];
        float r = bl * rbi;
#pragma unroll
        for (int m = 0; m < L; m++)
            r = fmaf(sw1[l * L + m], sspn[v][m], r);
        r += logits[l * NVOX + i16];
        scur[v][l] = r;
        if (last) out[l * NVOX + i16] = r;
    }
    __syncthreads();
    if (!last && tid < VPB) {
        int i = bid * VPB + tid;
        float vals[L]; float mx = -1e30f;
#pragma unroll
        for (int l = 0; l < L; l++) { vals[l] = scur[tid][l]; mx = fmaxf(mx, vals[l]); }
        float sum = 0.f;
#pragma unroll
        for (int l = 0; l < L; l++) { vals[l] = __expf(vals[l] - mx); sum += vals[l]; }
        float inv = 1.f / sum;
#pragma unroll
        for (int l = 0; l < L; l++) q[l * NVOX + i] = vals[l] * inv;
    }
}

extern "C" void kernel_launch(void* const* d_in, const int* in_sizes, int n_in,
                              void* d_out, int out_size, void* d_ws, size_t ws_size,
                              hipStream_t stream) {
    const float* image  = (const float*)d_in[0];
    const float* logits = (const float*)d_in[1];
    const float* Wsp    = (const float*)d_in[2];
    const float* Wbi    = (const float*)d_in[3];
    const float* Wc     = (const float*)d_in[4];
    float* out = (float*)d_out;

    char* ws = (char*)d_ws;
    float* Phi   = (float*)ws; ws += (size_t)UPAD * NVOX * sizeof(float);    // 3.67 MB
    float* nsp   = (float*)ws; ws += (size_t)NVOX * sizeof(float);
    float* q     = (float*)ws; ws += (size_t)L * NVOX * sizeof(float);
    float* spv   = (float*)ws; ws += (size_t)L * NVOX * sizeof(float);
    float* A2    = (float*)ws; ws += (size_t)2 * 22 * UPAD * sizeof(float);  // double buffer (22 rows)
    float* cu    = (float*)ws; ws += (size_t)256 * sizeof(float);
    float* W1    = (float*)ws; ws += (size_t)L * L * sizeof(float);
    float* W2    = (float*)ws; ws += (size_t)L * L * sizeof(float);

    phase_ab<<<67, 256, 0, stream>>>(image, logits, Wsp, Wbi, Wc,
                                     Phi, nsp, q, cu, W1, W2, A2);
    for (int it = 0; it < ITERS; it++) {
        float* A2cur  = A2 + (it & 1) * 22 * UPAD;
        float* A2next = A2 + ((it + 1) & 1) * 22 * UPAD;
        phase_p2<<<NG1B + L, 1024, 0, stream>>>(Phi, q, cu, W2, A2cur, spv);
        phase_p3<<<256, 256, 0, stream>>>(Phi, A2cur, A2next, spv, nsp,
                                          W1, logits, q, out,
                                          it == ITERS - 1 ? 1 : 0);
    }
}

// Round 12
// 161.878 us; speedup vs baseline: 2.0996x; 1.4390x over previous
//
#include <hip/hip_runtime.h>

#define L 21
#define NVOX 4096
#define ITERS 5
#define NU 210      // monomials of degree <= 4 in 6 vars
#define UPAD 224    // padded rows (210..223 are zero)
#define VPB 16      // voxels per block (P3)
#define NSPLIT 16   // u-splits in P3
#define USPL 14     // u per split (16*14 = 224)

// ---------------------------------------------------------------------------
// Phase AB (67 blocks x 256): Phi + nsp + q0(softmax of logits) + W-folds +
// cu table + zero both A2 buffers (22 rows each; row 21 = normalizer).
// ---------------------------------------------------------------------------
__global__ __launch_bounds__(256) void phase_ab(
    const float* __restrict__ img, const float* __restrict__ logits,
    const float* __restrict__ Wsp, const float* __restrict__ Wbi,
    const float* __restrict__ Wc,
    float* __restrict__ Phi, float* __restrict__ nsp, float* __restrict__ q,
    float* __restrict__ cu, float* __restrict__ W1, float* __restrict__ W2,
    float* __restrict__ A2)
{
    const int tid = threadIdx.x;
    const int bid = blockIdx.x;
    if (bid < 64) {
        int lane = tid & 63, w = tid >> 6;
        int i = bid * 64 + lane;
        int z = i >> 8, yy = (i >> 4) & 15, xx = i & 15;
        const float ia = 1.0f / 67.0f, ib = 1.0f / 3.0f;
        float f[6];
        f[0] = (float)z * ia; f[1] = (float)yy * ia; f[2] = (float)xx * ia;
        f[3] = img[i] * ib; f[4] = img[NVOX + i] * ib; f[5] = img[2 * NVOX + i] * ib;
        float p[6][5];
#pragma unroll
        for (int c = 0; c < 6; c++) {
            p[c][0] = 1.f;
#pragma unroll
            for (int k = 1; k < 5; k++) p[c][k] = p[c][k - 1] * f[c];
        }
        float hsv = 0.5f * (f[0]*f[0] + f[1]*f[1] + f[2]*f[2] +
                            f[3]*f[3] + f[4]*f[4] + f[5]*f[5]);
        float e0 = __expf(-hsv);
        int ulo = w * 56, uhi = ulo + 56;
        int u = 0;
        for (int a0 = 0; a0 <= 4; a0++)
        for (int a1 = 0; a1 <= 4 - a0; a1++)
        for (int a2 = 0; a2 <= 4 - a0 - a1; a2++)
        for (int a3 = 0; a3 <= 4 - a0 - a1 - a2; a3++)
        for (int a4 = 0; a4 <= 4 - a0 - a1 - a2 - a3; a4++)
        for (int a5 = 0; a5 <= 4 - a0 - a1 - a2 - a3 - a4; a5++) {
            if (u >= ulo && u < uhi)
                Phi[(size_t)u * NVOX + i] =
                    e0 * p[0][a0] * p[1][a1] * p[2][a2] * p[3][a3] * p[4][a4] * p[5][a5];
            u++;
        }
        if (w == 3)
            for (int uz = NU; uz < UPAD; uz++) Phi[(size_t)uz * NVOX + i] = 0.f;
        if (w == 0) {
            float hz = 0.f, hy = 0.f, hx = 0.f;
            for (int t = 0; t < 16; t++) {
                float dz = (float)(z - t), dy = (float)(yy - t), dx = (float)(xx - t);
                hz += __expf(-0.5f * dz * dz);
                hy += __expf(-0.5f * dy * dy);
                hx += __expf(-0.5f * dx * dx);
            }
            nsp[i] = hz * hy * hx;
        }
        if (w == 1) {   // softmax of logits -> q (iteration 0)
            float vals[L]; float mx = -1e30f;
#pragma unroll
            for (int l = 0; l < L; l++) { vals[l] = logits[l * NVOX + i]; mx = fmaxf(mx, vals[l]); }
            float sum = 0.f;
#pragma unroll
            for (int l = 0; l < L; l++) { vals[l] = __expf(vals[l] - mx); sum += vals[l]; }
            float inv = 1.f / sum;
#pragma unroll
            for (int l = 0; l < L; l++) q[l * NVOX + i] = vals[l] * inv;
        }
    } else if (bid == 64) {
        for (int e = tid; e < L * L; e += 256) {
            int r = e / L, c = e % L;
            float s1 = 0.f, s2 = 0.f;
            for (int k = 0; k < L; k++) {
                float wc = Wc[r * L + k];
                s1 = fmaf(wc, Wsp[k * L + c], s1);
                s2 = fmaf(wc, Wbi[k * L + c], s2);
            }
            W1[e] = s1; W2[e] = s2;
        }
    } else if (bid == 65) {
        const float invf[5] = {1.f, 1.f, 0.5f, 1.f / 6.f, 1.f / 24.f};
        float mine = 0.f;   // stays 0 for tid >= NU
        int v = 0;
        for (int a0 = 0; a0 <= 4; a0++)
        for (int a1 = 0; a1 <= 4 - a0; a1++)
        for (int a2 = 0; a2 <= 4 - a0 - a1; a2++)
        for (int a3 = 0; a3 <= 4 - a0 - a1 - a2; a3++)
        for (int a4 = 0; a4 <= 4 - a0 - a1 - a2 - a3; a4++)
        for (int a5 = 0; a5 <= 4 - a0 - a1 - a2 - a3 - a4; a5++) {
            if (v == tid)
                mine = invf[a0] * invf[a1] * invf[a2] * invf[a3] * invf[a4] * invf[a5];
            v++;
        }
        cu[tid] = mine;
    } else {
        // zero BOTH A2 double-buffers (22 rows each; g1 accumulates atomically)
        for (int e = tid; e < 2 * 22 * UPAD; e += 256) A2[e] = 0.f;
    }
}

// ---------------------------------------------------------------------------
// Phase P2 (231 blocks x 1024)  [R9 structure — max parallelism]:
//  bid<210: g1 for u=bid.  16 waves x 256-voxel chunks; one float4/row/lane;
//           22 accumulators (21 labels + normalizer); butterfly reduce;
//           W2/cu fold; atomicAdd into A2cur rows 0..21.
//  bid 210..230: spatial label bid-210: separable gaussian truncated to +-4
//           taps (dropped weight ~7.5e-6), compile-time weights, no LDS g[].
// ---------------------------------------------------------------------------
__global__ __launch_bounds__(1024) void phase_p2(
    const float* __restrict__ Phi, const float* __restrict__ q,
    const float* __restrict__ cu, const float* __restrict__ W2,
    float* __restrict__ A2cur, float* __restrict__ spv)
{
    __shared__ float buf[NVOX];
    __shared__ float tmp[NVOX];
    const int tid = threadIdx.x;
    const int bid = blockIdx.x;
    const float garr[5] = {1.0f, 0.60653066f, 0.13533528f,
                           0.011108997f, 3.3546263e-4f};
    if (bid < NU) {
        int lane = tid & 63, w = tid >> 6;   // wave id 0..15
        int i0 = w * 256;
        float4 p = ((const float4*)(Phi + (size_t)bid * NVOX + i0))[lane];
        float acc[22];
        acc[21] = p.x + p.y + p.z + p.w;     // normalizer partial
#pragma unroll
        for (int m = 0; m < L; m++) {
            float4 qv = ((const float4*)(q + m * NVOX + i0))[lane];
            acc[m] = fmaf(qv.x, p.x, fmaf(qv.y, p.y,
                     fmaf(qv.z, p.z, qv.w * p.w)));
        }
#pragma unroll
        for (int off = 32; off >= 1; off >>= 1)
#pragma unroll
            for (int m = 0; m < 22; m++)
                acc[m] += __shfl_xor(acc[m], off);
        if (lane < 22) {
            float val;
            if (lane < L) {
                float dot = 0.f;
#pragma unroll
                for (int m = 0; m < L; m++)
                    dot = fmaf(W2[lane * L + m], acc[m], dot);
                val = cu[bid] * dot;
            } else {
                val = cu[bid] * acc[21];
            }
            atomicAdd(&A2cur[lane * UPAD + bid], val);
        }
    } else {
        int l = bid - NU;
        for (int k = 0; k < 4; k++)
            buf[tid + 1024 * k] = q[l * NVOX + tid + 1024 * k];
        __syncthreads();
        for (int k = 0; k < 4; k++) {
            int idx = tid + 1024 * k;
            int x = idx & 15, base = idx & ~15;
            float ssum = 0.f;
#pragma unroll
            for (int dt = -4; dt <= 4; dt++) {
                int t = x + dt;
                int ad = dt < 0 ? -dt : dt;
                if (t >= 0 && t < 16) ssum = fmaf(garr[ad], buf[base + t], ssum);
            }
            tmp[idx] = ssum;
        }
        __syncthreads();
        for (int k = 0; k < 4; k++) {
            int idx = tid + 1024 * k;
            int y = (idx >> 4) & 15, base = idx & ~(15 << 4);
            float ssum = 0.f;
#pragma unroll
            for (int dt = -4; dt <= 4; dt++) {
                int t = y + dt;
                int ad = dt < 0 ? -dt : dt;
                if (t >= 0 && t < 16) ssum = fmaf(garr[ad], tmp[base + (t << 4)], ssum);
            }
            buf[idx] = ssum;
        }
        __syncthreads();
        for (int k = 0; k < 4; k++) {
            int idx = tid + 1024 * k;
            int z = idx >> 8, base = idx & 255;
            float ssum = 0.f;
#pragma unroll
            for (int dt = -4; dt <= 4; dt++) {
                int t = z + dt;
                int ad = dt < 0 ? -dt : dt;
                if (t >= 0 && t < 16) ssum = fmaf(garr[ad], buf[base + (t << 8)], ssum);
            }
            spv[l * NVOX + idx] = ssum;
        }
    }
}

// ---------------------------------------------------------------------------
// Phase P3: g2 + combine + softmax-for-next-iter.  256 blocks x 16 voxels.
// Reads A2cur rows 0..20 (bilateral) + row 21 (normalizer); zeroes A2next.
// float4 staging of sA/sN.
// ---------------------------------------------------------------------------
__global__ __launch_bounds__(256) void phase_p3(
    const float* __restrict__ Phi, const float* __restrict__ A2cur,
    float* __restrict__ A2next, const float* __restrict__ spv,
    const float* __restrict__ nsp, const float* __restrict__ W1,
    const float* __restrict__ logits, float* __restrict__ q,
    float* __restrict__ out, int last)
{
    __shared__ __align__(16) float sA[L * UPAD];
    __shared__ __align__(16) float sN[UPAD];
    __shared__ float red[22][NSPLIT][VPB];
    __shared__ float sw1[L * L];
    __shared__ float sspn[VPB][22];
    __shared__ float scur[VPB][22];
    const int tid = threadIdx.x;
    const int bid = blockIdx.x;
    const int v = tid & (VPB - 1);
    const int s = tid >> 4;
    const int i16 = bid * VPB + v;

    {   // zero next iteration's A2 buffer (22 rows; first 20 blocks cover it)
        int e = bid * 256 + tid;
        if (e < 22 * UPAD) A2next[e] = 0.f;
    }
    for (int e = tid; e < (L * UPAD) / 4; e += 256)
        ((float4*)sA)[e] = ((const float4*)A2cur)[e];
    if (tid < UPAD / 4)
        ((float4*)sN)[tid] = ((const float4*)(A2cur + L * UPAD))[tid];
    for (int e = tid; e < L * L; e += 256) sw1[e] = W1[e];
    {
        float rsp = 1.f / nsp[i16];
        for (int m = s; m < L; m += NSPLIT)
            sspn[v][m] = spv[m * NVOX + i16] * rsp;
    }
    __syncthreads();
    float acc[L], accN = 0.f;
#pragma unroll
    for (int m = 0; m < L; m++) acc[m] = 0.f;
    int u0 = s * USPL;
    for (int uu = 0; uu < USPL; uu++) {
        float p = Phi[(size_t)(u0 + uu) * NVOX + i16];
#pragma unroll
        for (int m = 0; m < L; m++)
            acc[m] = fmaf(sA[m * UPAD + u0 + uu], p, acc[m]);
        accN = fmaf(sN[u0 + uu], p, accN);
    }
#pragma unroll
    for (int m = 0; m < L; m++) red[m][s][v] = acc[m];
    red[21][s][v] = accN;
    __syncthreads();
    float b21 = 0.f;
#pragma unroll
    for (int ss = 0; ss < NSPLIT; ss++) b21 += red[21][ss][v];
    float rbi = 1.f / b21;
    for (int l = s; l < L; l += NSPLIT) {
        float bl = 0.f;
#pragma unroll
        for (int ss = 0; ss < NSPLIT; ss++) bl += red[l][ss][v];
        float r = bl * rbi;
#pragma unroll
        for (int m = 0; m < L; m++)
            r = fmaf(sw1[l * L + m], sspn[v][m], r);
        r += logits[l * NVOX + i16];
        scur[v][l] = r;
        if (last) out[l * NVOX + i16] = r;
    }
    __syncthreads();
    if (!last && tid < VPB) {
        int i = bid * VPB + tid;
        float vals[L]; float mx = -1e30f;
#pragma unroll
        for (int l = 0; l < L; l++) { vals[l] = scur[tid][l]; mx = fmaxf(mx, vals[l]); }
        float sum = 0.f;
#pragma unroll
        for (int l = 0; l < L; l++) { vals[l] = __expf(vals[l] - mx); sum += vals[l]; }
        float inv = 1.f / sum;
#pragma unroll
        for (int l = 0; l < L; l++) q[l * NVOX + i] = vals[l] * inv;
    }
}

extern "C" void kernel_launch(void* const* d_in, const int* in_sizes, int n_in,
                              void* d_out, int out_size, void* d_ws, size_t ws_size,
                              hipStream_t stream) {
    const float* image  = (const float*)d_in[0];
    const float* logits = (const float*)d_in[1];
    const float* Wsp    = (const float*)d_in[2];
    const float* Wbi    = (const float*)d_in[3];
    const float* Wc     = (const float*)d_in[4];
    float* out = (float*)d_out;

    char* ws = (char*)d_ws;
    float* Phi   = (float*)ws; ws += (size_t)UPAD * NVOX * sizeof(float);    // 3.67 MB
    float* nsp   = (float*)ws; ws += (size_t)NVOX * sizeof(float);
    float* q     = (float*)ws; ws += (size_t)L * NVOX * sizeof(float);
    float* spv   = (float*)ws; ws += (size_t)L * NVOX * sizeof(float);
    float* A2    = (float*)ws; ws += (size_t)2 * 22 * UPAD * sizeof(float);  // double buffer (22 rows)
    float* cu    = (float*)ws; ws += (size_t)256 * sizeof(float);
    float* W1    = (float*)ws; ws += (size_t)L * L * sizeof(float);
    float* W2    = (float*)ws; ws += (size_t)L * L * sizeof(float);

    phase_ab<<<67, 256, 0, stream>>>(image, logits, Wsp, Wbi, Wc,
                                     Phi, nsp, q, cu, W1, W2, A2);
    for (int it = 0; it < ITERS; it++) {
        float* A2cur  = A2 + (it & 1) * 22 * UPAD;
        float* A2next = A2 + ((it + 1) & 1) * 22 * UPAD;
        phase_p2<<<NU + L, 1024, 0, stream>>>(Phi, q, cu, W2, A2cur, spv);
        phase_p3<<<256, 256, 0, stream>>>(Phi, A2cur, A2next, spv, nsp,
                                          W1, logits, q, out,
                                          it == ITERS - 1 ? 1 : 0);
    }
}